// Round 1
// baseline (137.457 us; speedup 1.0000x reference)
//
#include <hip/hip_runtime.h>
#include <hip/hip_bf16.h>

// PointConv: N=32768 points, E=786432 edges (sorted by out_index), K<=64
// product[n][c][m] = inv_n * sum_edges x_in[src][c] * celu(celu(pos_local@W1)@W2)[m]
// out[n][k] = product[n].flat(1024) @ W3[1024][64] + b3[k]
//
// R13: FUSED final GEMM into agg_kernel. The per-point product is packed to
// f16 in registers at flush, staged to LDS (reusing H2L space) in a permuted
// k' order (k' = q*256 + r*16 + mt*4 + i) so each lane writes contiguous 16B
// chunks; W3frag is built with the inverse permutation so fragments agree.
// Eliminates the 64MB Pf16 write + 67MB read round-trip and gemm_kernel.

typedef __attribute__((ext_vector_type(8))) short short8;
typedef __attribute__((ext_vector_type(4))) float f32x4;
typedef __attribute__((ext_vector_type(2))) unsigned int u32x2;
typedef __attribute__((ext_vector_type(4))) unsigned int u32x4;
typedef __fp16 f16x2 __attribute__((ext_vector_type(2)));
typedef __fp16 f16x8 __attribute__((ext_vector_type(8)));

static __device__ __forceinline__ int rfl(int v){
    return __builtin_amdgcn_readfirstlane(v);
}
static __device__ __forceinline__ float celu1(float x){
    return x > 0.0f ? x : (__expf(x) - 1.0f);
}
static __device__ __forceinline__ unsigned int pkh(float lo, float hi){
    f16x2 t = __builtin_amdgcn_cvt_pkrtz(lo, hi);
    return __builtin_bit_cast(unsigned int, t);
}
// round-to-nearest-even f16 pack (matches previous (__fp16) casts of P)
static __device__ __forceinline__ unsigned int pkh_rte(float lo, float hi){
    unsigned short a = __builtin_bit_cast(unsigned short, (__fp16)lo);
    unsigned short b = __builtin_bit_cast(unsigned short, (__fp16)hi);
    return (unsigned int)a | ((unsigned int)b << 16);
}

// ---------------- Kernel 0: seg boundaries + W3/W2 prep (merged) -------------
// W3frag is fragment-ordered for n-tile t, K-chunk kk with the PERMUTED k':
//   k' = q*256 + r*16 + mt*4 + i   <->   k = (q*4+i)*64 + mt*16 + r
// so the agg epilogue's A-side (flush-register order) and B-side agree.
__global__ void setup_kernel(const int* __restrict__ out_index,
                             int* __restrict__ seg_start, int E, int N,
                             const float* __restrict__ W3, const float* __restrict__ W2,
                             __fp16* __restrict__ W3frag,
                             unsigned int* __restrict__ W2f16)
{
    int o = blockIdx.x * blockDim.x + threadIdx.x;
    if (o < E) {
        int cur = out_index[o];
        if (o == 0) {
            for (int v = 0; v <= cur; ++v) seg_start[v] = 0;
        } else {
            int prev = out_index[o - 1];
            for (int v = prev + 1; v <= cur; ++v) seg_start[v] = o;
        }
        if (o == E - 1) {
            for (int v = cur + 1; v <= N; ++v) seg_start[v] = E;
        }
    }
    if (o < 65536) {
        int j    = o & 7;
        int lane = (o >> 3) & 63;
        int t    = (o >> 9) & 3;
        int kk   = o >> 11;
        int kp = kk * 32 + (lane >> 4) * 8 + j;      // permuted k'
        int qq = kp >> 8;
        int rr = (kp >> 4) & 15;
        int mt = (kp >> 2) & 3;
        int ii = kp & 3;
        int k = (qq * 4 + ii) * 64 + mt * 16 + rr;   // true flat k = c*64 + m
        int n = t * 16 + (lane & 15);
        W3frag[o] = (__fp16)W3[k * 64 + n];
    } else if (o < 65536 + 1024) {
        int o2 = o - 65536;
        int nt   = o2 >> 8;
        int lane = (o2 >> 2) & 63;
        int d    = o2 & 3;
        int q = lane >> 4, rr = lane & 15;
        unsigned int v = 0;
        if (q < 2) {
            int k0 = q * 8 + 2 * d;
            int n = nt * 16 + rr;
            v = pkh(W2[k0 * 64 + n], W2[(k0 + 1) * 64 + n]);
        }
        W2f16[o2] = v;
    }
}

// ---------------- Kernel 1: edge aggregation + fused output GEMM -------------
// Wave w owns points [2w, 2w+2); block owns 8 points. Main loop identical to
// R12 except flushes pack P to registers (pkP0/pkP1) instead of global.
// Epilogue: stage P to LDS (XOR-swizzled rows), per-wave 16-col GEMM vs W3frag.
__global__ __launch_bounds__(256) void agg_kernel(
    const float* __restrict__ x_in, const float* __restrict__ pos_in,
    const float* __restrict__ pos_out, const int* __restrict__ in_index,
    const int* __restrict__ seg_start, const float* __restrict__ W1,
    const unsigned int* __restrict__ W2f16, const __fp16* __restrict__ W3frag,
    const float* __restrict__ b3, float* __restrict__ out, int E)
{
    __shared__ __align__(16) unsigned char ldsraw[4 * 9216];
    int lane = threadIdx.x & 63;
    int wv = threadIdx.x >> 6;
    unsigned char* H2L = ldsraw + wv * 9216;   // staging 0..3071; tile rows m*144
    int w = blockIdx.x * 4 + wv;

    int r = lane & 15;
    int q = lane >> 4;
    int l31 = lane & 31;
    bool hihalf = lane >= 32;
    int vq = 32 * q;                           // byte-addr component for bpermute

    // zero block for padded-K A-frag lanes (bytes 9200..9215 never written)
    if (lane == 0) *(u32x4*)(H2L + 9200) = (u32x4){0u, 0u, 0u, 0u};

    // W2 B-frags (constant)
    f16x8 bfr[4];
    #pragma unroll
    for (int nt = 0; nt < 4; ++nt)
        bfr[nt] = __builtin_bit_cast(f16x8, *((const u32x4*)W2f16 + nt * 64 + lane));

    // W1 columns (uniform -> SGPRs)
    float w1a[16], w1b[16], w1c[16];
    #pragma unroll
    for (int c = 0; c < 16; ++c) { w1a[c] = W1[c]; w1b[c] = W1[16 + c]; w1c[c] = W1[32 + c]; }

    // per-wave point table (2 points, wave-uniform)
    int s3[3];
    #pragma unroll
    for (int i = 0; i < 3; ++i) s3[i] = rfl(seg_start[w * 2 + i]);
    int cf[2], cc[2], p[3];
    p[0] = 0;
    #pragma unroll
    for (int i = 0; i < 2; ++i) {
        cf[i] = s3[i + 1] - s3[i];
        cc[i] = cf[i] > 64 ? 64 : cf[i];
        p[i + 1] = p[i] + (cc[i] > 32 ? 2 : 1);
    }
    int ns = p[2];                             // total 32-slot steps, 2..4

    // descriptor for step t (wave-uniform; t >= ns yields rem<=0 -> all-pad)
    #define STEP_DESC(t, nS, cfS, remS, ebS)                         \
        {                                                            \
            int i_ = 0, pi_ = 0;                                     \
            if ((t) >= p[1]) { i_ = 1; pi_ = p[1]; }                 \
            int cf_ = cf[0], cc_ = cc[0], sg_ = s3[0];               \
            if (i_ >= 1) { cf_ = cf[1]; cc_ = cc[1]; sg_ = s3[1]; }  \
            int kb_ = ((t) - pi_) * 32;                              \
            (nS) = w * 2 + i_; (cfS) = cf_;                          \
            (remS) = cc_ - kb_; (ebS) = sg_ + kb_;                   \
        }

    f32x4 C[4];
    #pragma unroll
    for (int mt = 0; mt < 4; ++mt) C[mt] = (f32x4){0.f, 0.f, 0.f, 0.f};
    int cur_n = w * 2;
    int cur_cf = cf[0];

    // packed f16 products for the wave's 2 points (static reg arrays).
    // Mid-loop flush is always point slot 0; final flush always slot 1.
    unsigned int pkP0[8], pkP1[8];
    #pragma unroll
    for (int i = 0; i < 8; ++i) { pkP0[i] = 0u; pkP1[i] = 0u; }

    // ---- prologue: batch 0 descriptors + idx + pos prefetch ----
    int nA, cfA, remA, ebA, nB, cfB, remB, ebB;
    STEP_DESC(0, nA, cfA, remA, ebA)
    STEP_DESC(1, nB, cfB, remB, ebB)
    int nH = hihalf ? nB : nA;
    int ebH = hihalf ? ebB : ebA;
    int idx0 = ebH + l31; idx0 = idx0 < E ? idx0 : E - 1;
    int idxs = in_index[idx0];                 // lane l -> src of slot l
    float pox = pos_out[nH * 3 + 0];
    float poy = pos_out[nH * 3 + 1];
    float poz = pos_out[nH * 3 + 2];
    float pi0 = pos_in[idxs * 3 + 0];
    float pi1 = pos_in[idxs * 3 + 1];
    float pi2 = pos_in[idxs * 3 + 2];

    #pragma unroll 1
    for (int b = 0; b < 2; ++b) {
        if (2 * b >= ns) break;

        // ---- prefetch next batch: descriptors + idx vector ----
        int nA2, cfA2, remA2, ebA2, nB2, cfB2, remB2, ebB2;
        STEP_DESC(2 * b + 2, nA2, cfA2, remA2, ebA2)
        STEP_DESC(2 * b + 3, nB2, cfB2, remB2, ebB2)
        int nH2 = hihalf ? nB2 : nA2;
        int ebH2 = hihalf ? ebB2 : ebA2;
        int idx2 = ebH2 + l31; idx2 = idx2 < E ? idx2 : E - 1;
        int idxs_next = in_index[idx2];
        float pox2 = pos_out[nH2 * 3 + 0];
        float poy2 = pos_out[nH2 * 3 + 1];
        float poz2 = pos_out[nH2 * 3 + 2];

        // ---- x A-frags: src via bpermute of idxs (loaded last iter) ----
        f16x8 ax[2];
        #pragma unroll
        for (int h = 0; h < 2; ++h) {
            int remS = h ? remB : remA;
            float xv[8];
            #pragma unroll
            for (int jj = 0; jj < 8; ++jj) {
                // slot = 32h + 8q + jj; bpermute byte addr = 4*slot
                int s = __builtin_amdgcn_ds_bpermute(128 * h + vq + 4 * jj, idxs);
                float x = x_in[s * 16 + r];
                xv[jj] = ((8 * q + jj) < remS) ? x : 0.0f;
            }
            u32x4 t;
            #pragma unroll
            for (int d = 0; d < 4; ++d) t[d] = pkh(xv[2 * d], xv[2 * d + 1]);
            ax[h] = __builtin_bit_cast(f16x8, t);
        }

        // ---- h1 (lane = slot): pos already prefetched ----
        float d0 = pi0 - pox;
        float d1 = pi1 - poy;
        float d2 = pi2 - poz;
        unsigned int hp[8];
        #pragma unroll
        for (int cp = 0; cp < 8; ++cp) {
            float a0 = celu1(fmaf(d0, w1a[2 * cp],     fmaf(d1, w1b[2 * cp],     d2 * w1c[2 * cp])));
            float a1 = celu1(fmaf(d0, w1a[2 * cp + 1], fmaf(d1, w1b[2 * cp + 1], d2 * w1c[2 * cp + 1])));
            hp[cp] = pkh(a0, a1);
        }
        *(u32x4*)(H2L + lane * 48)      = (u32x4){hp[0], hp[1], hp[2], hp[3]};
        *(u32x4*)(H2L + lane * 48 + 16) = (u32x4){hp[4], hp[5], hp[6], hp[7]};
        f16x8 af[4];
        #pragma unroll
        for (int et = 0; et < 4; ++et) {
            int abase = (q < 2) ? ((et * 16 + r) * 48 + q * 16) : 9200;
            af[et] = __builtin_bit_cast(f16x8, *(const u32x4*)(H2L + abase));
        }

        // ---- h2 = celu(h1 @ W2) via MFMA; tile write H2L[m][slot] ----
        #pragma unroll
        for (int pp = 0; pp < 2; ++pp) {
            f32x4 D[4][2];
            #pragma unroll
            for (int et = 0; et < 4; ++et)
                #pragma unroll
                for (int j = 0; j < 2; ++j)
                    D[et][j] = __builtin_amdgcn_mfma_f32_16x16x32_f16(
                        af[et], bfr[2 * pp + j], (f32x4){0.f, 0.f, 0.f, 0.f}, 0, 0, 0);
            #pragma unroll
            for (int et = 0; et < 4; ++et)
                #pragma unroll
                for (int j = 0; j < 2; ++j) {
                    int nt = 2 * pp + j;
                    float v0 = celu1(D[et][j][0]);
                    float v1 = celu1(D[et][j][1]);
                    float v2 = celu1(D[et][j][2]);
                    float v3 = celu1(D[et][j][3]);
                    *(u32x2*)(H2L + (nt * 16 + r) * 144 + et * 32 + q * 8) =
                        (u32x2){pkh(v0, v1), pkh(v2, v3)};
                }
        }

        // ---- pos prefetch for next batch (idxs_next has landed by now) ----
        float pi0n = pos_in[idxs_next * 3 + 0];
        float pi1n = pos_in[idxs_next * 3 + 1];
        float pi2n = pos_in[idxs_next * 3 + 2];

        // ---- P accumulation per half, flush to registers on transitions ----
        #pragma unroll
        for (int h = 0; h < 2; ++h) {
            int nS  = h ? nB : nA;
            int cfS = h ? cfB : cfA;
            if (rfl(nS) != cur_n) {
                float inv = cur_cf > 0 ? 1.0f / (float)cur_cf : 0.0f;
                #pragma unroll
                for (int mt = 0; mt < 4; ++mt) {
                    pkP0[2 * mt]     = pkh_rte(C[mt][0] * inv, C[mt][1] * inv);
                    pkP0[2 * mt + 1] = pkh_rte(C[mt][2] * inv, C[mt][3] * inv);
                }
                #pragma unroll
                for (int mt = 0; mt < 4; ++mt) C[mt] = (f32x4){0.f, 0.f, 0.f, 0.f};
                cur_n = nS; cur_cf = cfS;
            }
            #pragma unroll
            for (int mt = 0; mt < 4; ++mt) {
                f16x8 bb = __builtin_bit_cast(f16x8,
                    *(u32x4*)(H2L + (mt * 16 + r) * 144 + h * 64 + q * 16));
                C[mt] = __builtin_amdgcn_mfma_f32_16x16x32_f16(ax[h], bb, C[mt], 0, 0, 0);
            }
        }

        // ---- rotate pipeline registers ----
        nA = nA2; cfA = cfA2; remA = remA2; ebA = ebA2;
        nB = nB2; cfB = cfB2; remB = remB2; ebB = ebB2;
        idxs = idxs_next;
        pox = pox2; poy = poy2; poz = poz2;
        pi0 = pi0n; pi1 = pi1n; pi2 = pi2n;
    }

    // final flush (always the wave's second point -> slot 1)
    {
        float inv = cur_cf > 0 ? 1.0f / (float)cur_cf : 0.0f;
        #pragma unroll
        for (int mt = 0; mt < 4; ++mt) {
            pkP1[2 * mt]     = pkh_rte(C[mt][0] * inv, C[mt][1] * inv);
            pkP1[2 * mt + 1] = pkh_rte(C[mt][2] * inv, C[mt][3] * inv);
        }
    }
    #undef STEP_DESC

    // ================= fused output GEMM =================
    // P_lds layout: row = local point (0..7), 1024 f16 in k' order, 2048B/row,
    // 16B chunks XOR-swizzled by ((row&7)<<4). Rows 8..15 of the A-frag read a
    // zeroed broadcast slot at byte 16384.
    __syncthreads();   // all waves done with H2L staging
    {
        int row0 = wv * 2;
        unsigned int base0 = (unsigned int)(row0 * 2048 + q * 512 + r * 32);
        unsigned int base1 = base0 + 2048u;
        unsigned int swz0 = (unsigned int)((row0 & 7) << 4);
        unsigned int swz1 = (unsigned int)(((row0 + 1) & 7) << 4);
        *(u32x4*)(ldsraw + ((base0)       ^ swz0)) = (u32x4){pkP0[0], pkP0[1], pkP0[2], pkP0[3]};
        *(u32x4*)(ldsraw + ((base0 + 16u) ^ swz0)) = (u32x4){pkP0[4], pkP0[5], pkP0[6], pkP0[7]};
        *(u32x4*)(ldsraw + ((base1)       ^ swz1)) = (u32x4){pkP1[0], pkP1[1], pkP1[2], pkP1[3]};
        *(u32x4*)(ldsraw + ((base1 + 16u) ^ swz1)) = (u32x4){pkP1[4], pkP1[5], pkP1[6], pkP1[7]};
        if (threadIdx.x == 0) *(u32x4*)(ldsraw + 16384) = (u32x4){0u, 0u, 0u, 0u};
    }
    __syncthreads();
    {
        // wave wv computes out cols [wv*16, wv*16+16) for the block's 8 points
        const short8* Bp = (const short8*)W3frag + wv * 64 + lane;
        f32x4 Cg = (f32x4){0.f, 0.f, 0.f, 0.f};
        unsigned int abase = (unsigned int)(r * 2048 + q * 16);
        unsigned int aswz  = (unsigned int)((r & 7) << 4);
        bool arow_pad = (r >= 8);
        #pragma unroll 8
        for (int kk = 0; kk < 32; ++kk) {
            unsigned int ad = (abase + (unsigned int)(kk * 64)) ^ aswz;
            if (arow_pad) ad = 16384u;
            f16x8 a  = __builtin_bit_cast(f16x8, *(const u32x4*)(ldsraw + ad));
            f16x8 bf = __builtin_bit_cast(f16x8, Bp[kk * 256]);   // frag (kk*4 + wv)
            Cg = __builtin_amdgcn_mfma_f32_16x16x32_f16(a, bf, Cg, 0, 0, 0);
        }
        if (q < 2) {   // D rows q*4+i in [0,8) are the valid points
            int colbase = wv * 16 + r;
            float bias = b3[colbase];
            int prow = blockIdx.x * 8 + q * 4;
            #pragma unroll
            for (int i = 0; i < 4; ++i)
                out[(size_t)(prow + i) * 64 + colbase] = Cg[i] + bias;
        }
    }
}

extern "C" void kernel_launch(void* const* d_in, const int* in_sizes, int n_in,
                              void* d_out, int out_size, void* d_ws, size_t ws_size,
                              hipStream_t stream)
{
    const float* x_in    = (const float*)d_in[0];
    const float* pos_in  = (const float*)d_in[1];
    const float* pos_out = (const float*)d_in[2];
    const int* in_index  = (const int*)d_in[3];
    const int* out_index = (const int*)d_in[4];
    const float* W1 = (const float*)d_in[5];
    const float* W2 = (const float*)d_in[6];
    const float* W3 = (const float*)d_in[7];
    const float* b3 = (const float*)d_in[8];

    int N = in_sizes[0] / 16;    // 32768
    int E = in_sizes[3];         // 786432
    float* out = (float*)d_out;

    // workspace: seg (N+1) | W3frag (128KB) | W2f16 (4KB)
    char* ws = (char*)d_ws;
    int* seg = (int*)ws;
    size_t off = (((size_t)(N + 1) * 4 + 255) & ~(size_t)255);
    __fp16* W3frag = (__fp16*)(ws + off);
    off += (size_t)65536 * 2;
    unsigned int* W2f16 = (unsigned int*)(ws + off);

    setup_kernel<<<(E + 255) / 256, 256, 0, stream>>>(out_index, seg, E, N,
                                                      W3, W2, W3frag, W2f16);
    agg_kernel<<<N / 8, 256, 0, stream>>>(x_in, pos_in, pos_out, in_index, seg,
                                          W1, W2f16, W3frag, b3, out, E);
}